// Round 12
// baseline (528.275 us; speedup 1.0000x reference)
//
#include <hip/hip_runtime.h>
#include <cstdint>
#include <cstddef>

#define TSEQ 4096
#define BATCH 2
#define DIM 256
#define NHEAD 8
#define HDIM 32
#define NLAYER 4
#define FFDIM 1024
#define SPLITN 2048
#define MROWS (BATCH * TSEQ)   // 8192

#define QSCALE 0.2550784545f   // (1/sqrt(HD)) * log2(e), folded into q

typedef __attribute__((ext_vector_type(4))) float f32x4;
typedef __attribute__((ext_vector_type(8))) short bf16x8;

__device__ __forceinline__ short f2bf(float f) {
  union { float f; uint32_t u; } v; v.f = f;
  uint32_t r = v.u + 0x7fffu + ((v.u >> 16) & 1u);
  return (short)(r >> 16);
}

__device__ __forceinline__ float bf2f(short s) {
  union { uint32_t u; float f; } v; v.u = ((uint32_t)(uint16_t)s) << 16;
  return v.f;
}

__device__ __forceinline__ float fast_exp2(float x) {
#if __has_builtin(__builtin_amdgcn_exp2f)
  return __builtin_amdgcn_exp2f(x);
#else
  float r;
  asm volatile("v_exp_f32 %0, %1\n\ts_nop 1" : "=v"(r) : "v"(x));
  return r;
#endif
}

__device__ __forceinline__ uint32_t pack2bf(float a, float b) {
  union { float f; uint32_t u; } ua, ub; ua.f = a; ub.f = b;
  return ((ua.u + 0x8000u) >> 16) | ((ub.u + 0x8000u) & 0xffff0000u);
}

__device__ __forceinline__ float gelu_f(float x) {
  float u = 0.7978845608f * x * (1.0f + 0.044715f * x * x);
  u = fminf(fmaxf(u, -20.f), 20.f);
  float e = fast_exp2(2.885390082f * u);   // exp(2u)
  float t = (e - 1.0f) / (e + 1.0f);
  return 0.5f * x * (1.0f + t);
}

#define AS1 __attribute__((address_space(1)))
#define AS3 __attribute__((address_space(3)))
__device__ __forceinline__ void gload16(const void* g, void* l) {
  __builtin_amdgcn_global_load_lds((AS1 void*)g, (AS3 void*)l, 16, 0, 0);
}

// ---------------------------------------------------------------- weight prep
__global__ __launch_bounds__(256) void prep_w(
    const float* __restrict__ Wq, const float* __restrict__ Wk,
    const float* __restrict__ Wv, const float* __restrict__ Wo,
    const float* __restrict__ W1, const float* __restrict__ W2,
    short* __restrict__ qkvT, short* __restrict__ woT,
    short* __restrict__ w1T, short* __restrict__ w2T)
{
  const int NQKV = NLAYER * 768 * DIM;
  const int NO   = NLAYER * DIM * DIM;
  const int NF   = NLAYER * FFDIM * DIM;
  const int total = NQKV + NO + 2 * NF;
  for (int idx = blockIdx.x * 256 + threadIdx.x; idx < total; idx += gridDim.x * 256) {
    if (idx < NQKV) {                       // qkvT[l][n:768][k:256]
      const int l = idx / (768 * DIM);
      const int rem = idx - l * 768 * DIM;
      const int n = rem >> 8, k = rem & 255;
      const float* src = (n < 256) ? Wq : ((n < 512) ? Wk : Wv);
      qkvT[idx] = f2bf(src[((size_t)l * DIM + k) * DIM + (n & 255)]);
    } else if (idx < NQKV + NO) {           // woT[l][n:256][k:256]
      const int j = idx - NQKV;
      const int l = j >> 16;
      const int rem = j & 65535;
      const int n = rem >> 8, k = rem & 255;
      woT[j] = f2bf(Wo[((size_t)l * DIM + k) * DIM + n]);
    } else if (idx < NQKV + NO + NF) {      // w1T[l][n:1024][k:256]
      const int j = idx - NQKV - NO;
      const int l = j >> 18;
      const int rem = j & 262143;
      const int n = rem >> 8, k = rem & 255;
      w1T[j] = f2bf(W1[((size_t)l * DIM + k) * FFDIM + n]);
    } else {                                // w2T[l][n:256][k:1024]
      const int j = idx - NQKV - NO - NF;
      const int l = j >> 18;
      const int rem = j & 262143;
      const int n = rem >> 10, k = rem & 1023;
      w2T[j] = f2bf(W2[((size_t)l * FFDIM + k) * DIM + n]);
    }
  }
}

// ------------------------------------------------------------------- x prep
__global__ __launch_bounds__(256) void prep_x(
    const float* __restrict__ rows, const float* __restrict__ tte,
    float* __restrict__ xf, short* __restrict__ xb)
{
  const size_t idx = (size_t)blockIdx.x * 256 + threadIdx.x;  // float4 index
  float4 v = ((const float4*)rows)[idx];
  const size_t e = idx * 4;
  const int m = (int)(e >> 8);
  const int d = (int)(e & 255);
  const int t = m & (TSEQ - 1);
  const int bb = m >> 12;
  if (t < SPLITN) {
    const float4 a = ((const float4*)tte)[((size_t)bb * SPLITN + t) * (DIM / 4) + (d >> 2)];
    v.x += a.x; v.y += a.y; v.z += a.z; v.w += a.w;
  }
  ((float4*)xf)[idx] = v;
  short4 pk; pk.x = f2bf(v.x); pk.y = f2bf(v.y); pk.z = f2bf(v.z); pk.w = f2bf(v.w);
  ((short4*)xb)[idx] = pk;
}

// ---------------------------------------------------------------------- GEMM
// (m97 pattern, R8 config)  EPI: 1=qkv (+bias, q scaled, bf16)  3=gelu bf16
#define GBM 128
#define GBN 64
#define GBK 64

template<int EPI>
__global__ __launch_bounds__(256, 4) void gemm_bt(
    const short* __restrict__ A, const short* __restrict__ BT,
    const float* __restrict__ bias0, const float* __restrict__ bias1,
    const float* __restrict__ bias2, void* __restrict__ Cout,
    int M, int N, int K)
{
  __shared__ short As[GBM * GBK];
  __shared__ short Bs[GBN * GBK];
  const int tid = threadIdx.x;
  const int lane = tid & 63;
  const int wave = tid >> 6;
  const int wm = wave & 1, wn = wave >> 1;
  const int col = lane & 15, quad = lane >> 4;

  const short* Ab = A + (size_t)blockIdx.x * GBM * K;
  const short* Bb = BT + (size_t)blockIdx.y * GBN * K;

  const f32x4 fz = {0.f, 0.f, 0.f, 0.f};
  f32x4 acc[4][2];
#pragma unroll
  for (int i = 0; i < 4; ++i)
#pragma unroll
    for (int j = 0; j < 2; ++j) acc[i][j] = fz;

  for (int k0 = 0; k0 < K; k0 += GBK) {
#pragma unroll
    for (int p = 0; p < 4; ++p) {
      int i = p * 256 + tid;
      gload16(Ab + (size_t)(i >> 3) * K + k0 + (i & 7) * 8, &As[i * 8]);
    }
#pragma unroll
    for (int p = 0; p < 2; ++p) {
      int i = p * 256 + tid;
      gload16(Bb + (size_t)(i >> 3) * K + k0 + (i & 7) * 8, &Bs[i * 8]);
    }
    __syncthreads();
#pragma unroll
    for (int ks = 0; ks < GBK; ks += 32) {
      bf16x8 af[4], bfr[2];
#pragma unroll
      for (int tm = 0; tm < 4; ++tm)
        af[tm] = *(const bf16x8*)&As[(wm * 64 + tm * 16 + col) * GBK + ks + quad * 8];
#pragma unroll
      for (int tn = 0; tn < 2; ++tn)
        bfr[tn] = *(const bf16x8*)&Bs[(wn * 32 + tn * 16 + col) * GBK + ks + quad * 8];
#pragma unroll
      for (int tm = 0; tm < 4; ++tm)
#pragma unroll
        for (int tn = 0; tn < 2; ++tn)
          acc[tm][tn] = __builtin_amdgcn_mfma_f32_16x16x32_bf16(af[tm], bfr[tn], acc[tm][tn], 0, 0, 0);
    }
    __syncthreads();
  }

#pragma unroll
  for (int tm = 0; tm < 4; ++tm) {
    const int mbase = blockIdx.x * GBM + wm * 64 + tm * 16 + quad * 4;
#pragma unroll
    for (int tn = 0; tn < 2; ++tn) {
      const int n = blockIdx.y * GBN + wn * 32 + tn * 16 + col;
      float bv;
      if (EPI == 1) bv = (n < 256) ? bias0[n] : ((n < 512) ? bias1[n - 256] : bias2[n - 512]);
      else          bv = bias0[n];
#pragma unroll
      for (int r = 0; r < 4; ++r) {
        float v = acc[tm][tn][r] + bv;
        size_t off = (size_t)(mbase + r) * N + n;
        if (EPI == 1) {
          if (n < 256) v *= QSCALE;
          ((short*)Cout)[off] = f2bf(v);
        } else {
          ((short*)Cout)[off] = f2bf(gelu_f(v));
        }
      }
    }
  }
}

// ------------------------------------------------ GEMM + residual + LN fused
// (R8 config)  MODE 0: A bf16.  MODE 1: A = combined attn out from Opart/lpart.
template<int MODE>
__global__ __launch_bounds__(256, 3) void gemm_ln(
    const short* __restrict__ A, const float* __restrict__ Opart,
    const float* __restrict__ lpart,
    const short* __restrict__ BT, const float* __restrict__ bias,
    const float* __restrict__ xres,
    const float* __restrict__ gs, const float* __restrict__ gb,
    float* __restrict__ xoutf, short* __restrict__ xoutb, int K)
{
  __shared__ short As[32 * 64];
  __shared__ short Bs[256 * 64];
  __shared__ float ssum[4][32], ssq[4][32];
  const int tid = threadIdx.x;
  const int lane = tid & 63;
  const int wave = tid >> 6;
  const int col = lane & 15, quad = lane >> 4;
  const int m0 = blockIdx.x * 32;

  const f32x4 fz = {0.f, 0.f, 0.f, 0.f};
  f32x4 acc[2][4];
#pragma unroll
  for (int i = 0; i < 2; ++i)
#pragma unroll
    for (int j = 0; j < 4; ++j) acc[i][j] = fz;

  const int arow = tid >> 3;
  const int agr  = tid & 7;
  const int grow = m0 + arow;

  for (int k0 = 0; k0 < K; k0 += 64) {
    if (MODE == 0) {
      const bf16x8 av = *(const bf16x8*)(A + (size_t)grow * K + k0 + agr * 8);
      *(bf16x8*)&As[arow * 64 + ((agr ^ (arow & 7)) * 8)] = av;
    } else {
      const int tt = grow & (TSEQ - 1), bb = grow >> 12;
      const int head = (k0 >> 5) + (agr >= 4 ? 1 : 0);
      const size_t lidx = (size_t)(bb * 8 + head) * TSEQ + tt;
      const float l = lpart[lidx] + lpart[(size_t)16 * TSEQ + lidx];
      const float li = 1.0f / l;
      const size_t obase = (size_t)grow * DIM + k0 + agr * 8;
      const float4 a0 = *(const float4*)(Opart + obase);
      const float4 a1 = *(const float4*)(Opart + obase + 4);
      const float4 c0 = *(const float4*)(Opart + (size_t)MROWS * DIM + obase);
      const float4 c1 = *(const float4*)(Opart + (size_t)MROWS * DIM + obase + 4);
      uint4 w;
      w.x = pack2bf((a0.x + c0.x) * li, (a0.y + c0.y) * li);
      w.y = pack2bf((a0.z + c0.z) * li, (a0.w + c0.w) * li);
      w.z = pack2bf((a1.x + c1.x) * li, (a1.y + c1.y) * li);
      w.w = pack2bf((a1.z + c1.z) * li, (a1.w + c1.w) * li);
      *(uint4*)&As[arow * 64 + ((agr ^ (arow & 7)) * 8)] = w;
    }
#pragma unroll
    for (int p = 0; p < 8; ++p) {
      int i = p * 256 + tid;
      gload16(BT + (size_t)(i >> 3) * K + k0 + (i & 7) * 8, &Bs[i * 8]);
    }
    __syncthreads();
#pragma unroll
    for (int ks = 0; ks < 64; ks += 32) {
      bf16x8 af[2], bfr[4];
#pragma unroll
      for (int tm = 0; tm < 2; ++tm) {
        const int row = tm * 16 + col;
        const int g = (ks >> 3) + quad;
        af[tm] = *(const bf16x8*)&As[row * 64 + ((g ^ (row & 7)) * 8)];
      }
#pragma unroll
      for (int tn = 0; tn < 4; ++tn)
        bfr[tn] = *(const bf16x8*)&Bs[(wave * 64 + tn * 16 + col) * 64 + ks + quad * 8];
#pragma unroll
      for (int tm = 0; tm < 2; ++tm)
#pragma unroll
        for (int tn = 0; tn < 4; ++tn)
          acc[tm][tn] = __builtin_amdgcn_mfma_f32_16x16x32_bf16(af[tm], bfr[tn], acc[tm][tn], 0, 0, 0);
    }
    __syncthreads();
  }

  const float* resb = xres + (size_t)m0 * DIM;
#pragma unroll
  for (int tn = 0; tn < 4; ++tn) {
    const int n = wave * 64 + tn * 16 + col;
    const float bv = bias[n];
#pragma unroll
    for (int tm = 0; tm < 2; ++tm)
#pragma unroll
      for (int r = 0; r < 4; ++r) {
        const int row = tm * 16 + quad * 4 + r;
        acc[tm][tn][r] += bv + resb[(size_t)row * DIM + n];
      }
  }

#pragma unroll
  for (int tm = 0; tm < 2; ++tm)
#pragma unroll
    for (int r = 0; r < 4; ++r) {
      float s = 0.f, q = 0.f;
#pragma unroll
      for (int tn = 0; tn < 4; ++tn) { const float v = acc[tm][tn][r]; s += v; q += v * v; }
      s += __shfl_xor(s, 1); q += __shfl_xor(q, 1);
      s += __shfl_xor(s, 2); q += __shfl_xor(q, 2);
      s += __shfl_xor(s, 4); q += __shfl_xor(q, 4);
      s += __shfl_xor(s, 8); q += __shfl_xor(q, 8);
      if (col == 0) { const int row = tm * 16 + quad * 4 + r; ssum[wave][row] = s; ssq[wave][row] = q; }
    }
  __syncthreads();
  if (tid < 32) {
    const float S = ssum[0][tid] + ssum[1][tid] + ssum[2][tid] + ssum[3][tid];
    const float Q = ssq[0][tid] + ssq[1][tid] + ssq[2][tid] + ssq[3][tid];
    const float mu = S * (1.0f / DIM);
    const float var = Q * (1.0f / DIM) - mu * mu;
    ssum[0][tid] = mu;
    ssq[0][tid] = rsqrtf(var + 1e-5f);
  }
  __syncthreads();

#pragma unroll
  for (int tm = 0; tm < 2; ++tm)
#pragma unroll
    for (int tn = 0; tn < 4; ++tn) {
      const int n = wave * 64 + tn * 16 + col;
      const float g = gs[n], bb2 = gb[n];
#pragma unroll
      for (int r = 0; r < 4; ++r) {
        const int row = tm * 16 + quad * 4 + r;
        const float out = (acc[tm][tn][r] - ssum[0][row]) * ssq[0][row] * g + bb2;
        xoutf[(size_t)(m0 + row) * DIM + n] = out;
        xoutb[(size_t)(m0 + row) * DIM + n] = f2bf(out);
      }
    }
}

// ----------------------------------------------------------------- attention v3
// Key-split x2 (blockIdx.z).  Block = 256 queries of one (b,h); 4 waves x 64q
// (4 subtiles of 16).  kf/vf LDS reads amortized over 4 subtiles; blocks/CU
// halve -> barrier rounds per CU halve.  K staged via DMA hd-part planes;
// V staged from qkv as key-pairs (b32 swizzled writes, threads<128).
#define AKT 64
#define KSPL 1024
#define NKT (KSPL / AKT)

__global__ __launch_bounds__(256, 2) void attn_kernel(
    const short* __restrict__ qkv,
    float* __restrict__ Opart, float* __restrict__ lpart)
{
  __shared__ short Kbuf[2][AKT * HDIM];   // [part(4)][key(64)][8]  8 KB
  __shared__ short Vbuf[2][HDIM * AKT];   // [hd][key-swz]          8 KB
  __shared__ short Pall[4][64][72];       // per-wave P (64q x 64k) 36.9 KB
  __shared__ float Pdiag[4][16];

  const int tid = threadIdx.x;
  const int lane = tid & 63;
  const int wave = tid >> 6;
  const int col = lane & 15, quad = lane >> 4;
  const int bh = blockIdx.y;
  const int b = bh >> 3, h = bh & 7;
  const int hz = blockIdx.z;
  const int q0 = blockIdx.x * 256 + wave * 64;   // this wave's 64 queries

  short (*P)[72] = Pall[wave];

  const short* qbase = qkv + (size_t)b * TSEQ * 768 + h * HDIM;
  const short* kbase = qbase + 256;
  const short* vcol  = qbase + 512;

  const short* ksrc = kbase + (size_t)(hz * KSPL + (tid & 63)) * 768 + (tid >> 6) * 8;

  const int vhg = (tid & 127) >> 5, vpr = tid & 31;
  const int vva = vpr >> 2, vb8 = (vpr & 3) * 2;
  const short* vsrc = vcol + (size_t)(hz * KSPL + 2 * vpr) * 768 + vhg * 8;
  const bool vact = (tid < 128);

  bf16x8 qf[4];
#pragma unroll
  for (int qs = 0; qs < 4; ++qs)
    qf[qs] = *(const bf16x8*)(qbase + (size_t)(q0 + qs * 16 + col) * 768 + quad * 8);

  bf16x8 ones;
#pragma unroll
  for (int i = 0; i < 8; ++i) ones[i] = (short)0x3F80;

  const f32x4 fz = {0.f, 0.f, 0.f, 0.f};
  f32x4 o[4][2];
#pragma unroll
  for (int i = 0; i < 4; ++i) { o[i][0] = fz; o[i][1] = fz; }
  f32x4 lacc[4] = {fz, fz, fz, fz};

  gload16(ksrc, &Kbuf[0][tid * 8]);
  bf16x8 vn0, vn1;
  if (vact) {
    const bf16x8 v0 = *(const bf16x8*)vsrc;
    const bf16x8 v1 = *(const bf16x8*)(vsrc + 768);
#pragma unroll
    for (int j = 0; j < 8; ++j) {
      const uint32_t w = (uint32_t)(uint16_t)v0[j] | ((uint32_t)(uint16_t)v1[j] << 16);
      *(uint32_t*)&Vbuf[0][(vhg * 8 + j) * 64 + ((vva ^ j) * 8) + vb8] = w;
    }
    vn0 = *(const bf16x8*)(vsrc + (size_t)AKT * 768);
    vn1 = *(const bf16x8*)(vsrc + (size_t)AKT * 768 + 768);
  }

  int cur = 0;
  for (int t = 0; t < NKT; ++t) {
    __syncthreads();
    if (t + 1 < NKT) {
      gload16(ksrc + (size_t)(t + 1) * AKT * 768, &Kbuf[1 - cur][tid * 8]);
      if (vact) {
#pragma unroll
        for (int j = 0; j < 8; ++j) {
          const uint32_t w = (uint32_t)(uint16_t)vn0[j] | ((uint32_t)(uint16_t)vn1[j] << 16);
          *(uint32_t*)&Vbuf[1 - cur][(vhg * 8 + j) * 64 + ((vva ^ j) * 8) + vb8] = w;
        }
        if (t + 2 < NKT) {
          vn0 = *(const bf16x8*)(vsrc + (size_t)(t + 2) * AKT * 768);
          vn1 = *(const bf16x8*)(vsrc + (size_t)(t + 2) * AKT * 768 + 768);
        }
      }
    }
    const short* kb = Kbuf[cur];
    const short* vb = Vbuf[cur];

    // ---- S phase: kf read once per key-subtile, reused by 4 q-subtiles
#pragma unroll
    for (int st = 0; st < 4; ++st) {
      const bf16x8 kf = *(const bf16x8*)&kb[(quad * 64 + st * 16 + col) * 8];
#pragma unroll
      for (int qs = 0; qs < 4; ++qs) {
        const f32x4 s = __builtin_amdgcn_mfma_f32_16x16x32_bf16(kf, qf[qs], fz, 0, 0, 0);
        uint2 w;
        w.x = pack2bf(fast_exp2(s[0]), fast_exp2(s[1]));
        w.y = pack2bf(fast_exp2(s[2]), fast_exp2(s[3]));
        *(uint2*)&P[qs * 16 + col][st * 16 + quad * 4] = w;
      }
    }
    asm volatile("s_waitcnt lgkmcnt(0)" ::: "memory");

    // ---- PV phase: vf read once per (kh,hh), reused by 4 q-subtiles
#pragma unroll
    for (int kh = 0; kh < 2; ++kh) {
      bf16x8 vf[2];
#pragma unroll
      for (int hh = 0; hh < 2; ++hh) {
        const int hd = hh * 16 + col;
        vf[hh] = *(const bf16x8*)&vb[hd * AKT + (((kh * 4 + quad) ^ (hd & 7)) * 8)];
      }
#pragma unroll
      for (int qs = 0; qs < 4; ++qs) {
        const bf16x8 pf = *(const bf16x8*)&P[qs * 16 + col][kh * 32 + quad * 8];
        o[qs][0] = __builtin_amdgcn_mfma_f32_16x16x32_bf16(pf, vf[0], o[qs][0], 0, 0, 0);
        o[qs][1] = __builtin_amdgcn_mfma_f32_16x16x32_bf16(pf, vf[1], o[qs][1], 0, 0, 0);
        lacc[qs] = __builtin_amdgcn_mfma_f32_16x16x32_bf16(pf, ones, lacc[qs], 0, 0, 0);
      }
    }
    cur ^= 1;
  }

  // ---- diagonal self-key (elementwise) for test-query blocks
  if (hz == 1 && blockIdx.x >= SPLITN / 256) {
#pragma unroll
    for (int qs = 0; qs < 4; ++qs) {
      const int qd = q0 + qs * 16;
      const bf16x8 kf = *(const bf16x8*)(kbase + (size_t)(qd + col) * 768 + quad * 8);
      const f32x4 sd = __builtin_amdgcn_mfma_f32_16x16x32_bf16(kf, qf[qs], fz, 0, 0, 0);
      float ps = 0.f;
#pragma unroll
      for (int r = 0; r < 4; ++r)
        if (quad * 4 + r == col) ps = fast_exp2(sd[r]);
      if (quad == (col >> 2)) Pdiag[wave][col] = ps;
      asm volatile("s_waitcnt lgkmcnt(0)" ::: "memory");
      const f32x4 pv = *(const f32x4*)&Pdiag[wave][quad * 4];
#pragma unroll
      for (int r = 0; r < 4; ++r) {
        lacc[qs][r] += pv[r];
        const size_t vrow = (size_t)(qd + quad * 4 + r) * 768;
#pragma unroll
        for (int hh = 0; hh < 2; ++hh)
          o[qs][hh][r] += pv[r] * bf2f(vcol[vrow + hh * 16 + col]);
      }
      asm volatile("s_waitcnt lgkmcnt(0)" ::: "memory");
    }
  }

  // ---- partial epilogue (un-normalized fp32 O + l)
  float* Ob = Opart + (size_t)hz * MROWS * DIM;
  float* lb = lpart + (size_t)hz * 16 * TSEQ + (size_t)bh * TSEQ;
#pragma unroll
  for (int qs = 0; qs < 4; ++qs) {
    const f32x4 la = lacc[qs];
    const int qq = q0 + qs * 16 + quad * 4;
    const int rowb = b * TSEQ + qq;
#pragma unroll
    for (int r = 0; r < 4; ++r) {
      if (col == 0) lb[qq + r] = la[r];
#pragma unroll
      for (int hh = 0; hh < 2; ++hh)
        Ob[(size_t)(rowb + r) * DIM + h * HDIM + hh * 16 + col] = o[qs][hh][r];
    }
  }
}

// ------------------------------------------------------------------ launch
extern "C" void kernel_launch(void* const* d_in, const int* in_sizes, int n_in,
                              void* d_out, int out_size, void* d_ws, size_t ws_size,
                              hipStream_t stream)
{
  const float* rows = (const float*)d_in[0];
  const float* tte  = (const float*)d_in[1];
  const float* Wq = (const float*)d_in[2];  const float* bq = (const float*)d_in[3];
  const float* Wk = (const float*)d_in[4];  const float* bk = (const float*)d_in[5];
  const float* Wv = (const float*)d_in[6];  const float* bv = (const float*)d_in[7];
  const float* Wo = (const float*)d_in[8];  const float* bo = (const float*)d_in[9];
  const float* W1 = (const float*)d_in[10]; const float* b1 = (const float*)d_in[11];
  const float* W2 = (const float*)d_in[12]; const float* b2 = (const float*)d_in[13];
  const float* ln1s = (const float*)d_in[14]; const float* ln1b = (const float*)d_in[15];
  const float* ln2s = (const float*)d_in[16]; const float* ln2b = (const float*)d_in[17];

  char* p = (char*)d_ws;
  float* xf   = (float*)p;  p += (size_t)MROWS * DIM * 4;
  short* xb   = (short*)p;  p += (size_t)MROWS * DIM * 2;
  short* qkv  = (short*)p;  p += (size_t)MROWS * 768 * 2;
  short* hb   = (short*)p;  p += (size_t)MROWS * FFDIM * 2;
  float* Opart = (float*)p; p += (size_t)2 * MROWS * DIM * 4;
  float* lpart = (float*)p; p += (size_t)2 * 16 * TSEQ * 4;
  short* qkvT = (short*)p;  p += (size_t)NLAYER * 768 * DIM * 2;
  short* woT  = (short*)p;  p += (size_t)NLAYER * DIM * DIM * 2;
  short* w1T  = (short*)p;  p += (size_t)NLAYER * FFDIM * DIM * 2;
  short* w2T  = (short*)p;  p += (size_t)NLAYER * DIM * FFDIM * 2;

  prep_w<<<2048, 256, 0, stream>>>(Wq, Wk, Wv, Wo, W1, W2, qkvT, woT, w1T, w2T);
  prep_x<<<MROWS * DIM / 4 / 256, 256, 0, stream>>>(rows, tte, xf, xb);

  for (int l = 0; l < NLAYER; ++l) {
    gemm_bt<1><<<dim3(MROWS / GBM, 768 / GBN), 256, 0, stream>>>(
        xb, qkvT + (size_t)l * 768 * DIM, bq + l * DIM, bk + l * DIM, bv + l * DIM,
        qkv, MROWS, 768, DIM);
    attn_kernel<<<dim3(TSEQ / 256, BATCH * NHEAD, 2), 256, 0, stream>>>(qkv, Opart, lpart);
    gemm_ln<1><<<MROWS / 32, 256, 0, stream>>>(
        nullptr, Opart, lpart, woT + (size_t)l * DIM * DIM, bo + l * DIM, xf,
        ln1s + l * DIM, ln1b + l * DIM, xf, xb, DIM);
    gemm_bt<3><<<dim3(MROWS / GBM, FFDIM / GBN), 256, 0, stream>>>(
        xb, w1T + (size_t)l * FFDIM * DIM, b1 + l * FFDIM, nullptr, nullptr,
        hb, MROWS, FFDIM, DIM);
    float* xo = (l == NLAYER - 1) ? (float*)d_out : xf;
    gemm_ln<0><<<MROWS / 32, 256, 0, stream>>>(
        hb, nullptr, nullptr, w2T + (size_t)l * DIM * FFDIM,
        b2 + l * DIM, xf, ln2s + l * DIM, ln2b + l * DIM, xo, xb, FFDIM);
  }
}